// Round 1
// baseline (1155.412 us; speedup 1.0000x reference)
//
#include <hip/hip_runtime.h>
#include <hip/hip_bf16.h>
#include <math.h>

// Problem constants (B=4, S=2048 -> T=8192 tokens)
#define T_TOK 8192
#define DM    1024
#define NE    8
#define HD    4096

typedef __bf16 bf16;
typedef __attribute__((ext_vector_type(8))) __bf16 bf16x8;
typedef __attribute__((ext_vector_type(4))) float  f32x4;

__device__ __forceinline__ void gl_lds16(const void* g, void* l) {
  __builtin_amdgcn_global_load_lds((const __attribute__((address_space(1))) void*)g,
                                   (__attribute__((address_space(3))) void*)l, 16, 0, 0);
}

// Raw barrier / counted waitcnt: keep prefetch loads in flight across the barrier.
#define RAW_BARRIER() asm volatile("s_barrier" ::: "memory")
#define WAIT_VM8()    asm volatile("s_waitcnt vmcnt(8)" ::: "memory")

__device__ __forceinline__ int imin(int a, int b) { return a < b ? a : b; }

// ---------------- zero out + counts ----------------
__global__ void zero_kernel(float* __restrict__ out, int* __restrict__ counts) {
  size_t stride = (size_t)gridDim.x * blockDim.x;
  size_t n4 = (size_t)T_TOK * DM / 4;
  for (size_t i = (size_t)blockIdx.x * blockDim.x + threadIdx.x; i < n4; i += stride) {
    float4 z = {0.f, 0.f, 0.f, 0.f};
    ((float4*)out)[i] = z;
  }
  if (blockIdx.x == 0 && threadIdx.x < NE) counts[threadIdx.x] = 0;
}

// ---------------- transpose + cvt: in [e][R][C] fp32 -> out [e][C][R] bf16 ----------------
__global__ void transpose_cvt_kernel(const float* __restrict__ in, bf16* __restrict__ out,
                                     int R, int C) {
  __shared__ float tile[64][65];
  int e = blockIdx.z;
  int c0 = blockIdx.x * 64, r0 = blockIdx.y * 64;
  int tid = threadIdx.x;
  int lr = tid >> 2, lc = (tid & 3) * 16;
  const float* src = in + ((size_t)e * R + r0 + lr) * C + c0 + lc;
#pragma unroll
  for (int q = 0; q < 4; ++q) {
    float4 v = *(const float4*)(src + q * 4);
    tile[lr][lc + q * 4 + 0] = v.x;
    tile[lr][lc + q * 4 + 1] = v.y;
    tile[lr][lc + q * 4 + 2] = v.z;
    tile[lr][lc + q * 4 + 3] = v.w;
  }
  __syncthreads();
  int oc = tid >> 3;      // 0..31
  int rchunk = tid & 7;   // 0..7
#pragma unroll
  for (int q = 0; q < 2; ++q) {
    int ocq = oc + q * 32;
    bf16x8 o;
#pragma unroll
    for (int k = 0; k < 8; ++k) o[k] = (bf16)tile[rchunk * 8 + k][ocq];
    *(bf16x8*)(out + ((size_t)e * C + c0 + ocq) * R + r0 + rchunk * 8) = o;
  }
}

// ---------------- gating: logits (double), softmax, top-2, compaction + x->bf16 ----------------
__global__ void gating_kernel(const float* __restrict__ x, const float* __restrict__ Wg,
                              const float* __restrict__ bg, int* __restrict__ counts,
                              int* __restrict__ tokl, float* __restrict__ wgt,
                              bf16* __restrict__ xb) {
  int t = blockIdx.x * 4 + (threadIdx.x >> 6);
  int lane = threadIdx.x & 63;
  if (t >= T_TOK) return;
  double acc[NE];
#pragma unroll
  for (int e = 0; e < NE; ++e) acc[e] = 0.0;
  const float* xr = x + (size_t)t * DM;
  bf16* xbr = xb + (size_t)t * DM;
  for (int d = lane; d < DM; d += 64) {
    float xv = xr[d];
    xbr[d] = (bf16)xv;   // fused fp32->bf16 conversion (replaces cvt_x kernel)
#pragma unroll
    for (int e = 0; e < NE; ++e) acc[e] += (double)xv * (double)Wg[d * NE + e];
  }
#pragma unroll
  for (int e = 0; e < NE; ++e)
    for (int o = 32; o > 0; o >>= 1) acc[e] += __shfl_down(acc[e], o, 64);
  if (lane == 0) {
    float l[NE], w[NE];
    float m = -1e30f;
#pragma unroll
    for (int e = 0; e < NE; ++e) { l[e] = (float)acc[e] + bg[e]; m = fmaxf(m, l[e]); }
    float s = 0.f;
#pragma unroll
    for (int e = 0; e < NE; ++e) { w[e] = expf(l[e] - m); s += w[e]; }
    float inv = 1.f / s;
#pragma unroll
    for (int e = 0; e < NE; ++e) w[e] *= inv;
    int e1 = 0; float v1 = w[0];
#pragma unroll
    for (int e = 1; e < NE; ++e) if (w[e] > v1) { v1 = w[e]; e1 = e; }
    int e2 = -1; float v2 = -1.f;
#pragma unroll
    for (int e = 0; e < NE; ++e) if (e != e1 && w[e] > v2) { v2 = w[e]; e2 = e; }
    int s1 = atomicAdd(&counts[e1], 1);
    tokl[e1 * T_TOK + s1] = t; wgt[e1 * T_TOK + s1] = v1;
    int s2 = atomicAdd(&counts[e2], 1);
    tokl[e2 * T_TOK + s2] = t; wgt[e2 * T_TOK + s2] = v2;
  }
}

// ---------------- scan ----------------
__global__ void scan_kernel(const int* __restrict__ counts, int* __restrict__ offsets) {
  if (threadIdx.x == 0 && blockIdx.x == 0) {
    int s = 0;
#pragma unroll
    for (int e = 0; e < NE; ++e) { offsets[e] = s; s += counts[e]; }
    offsets[NE] = s;
  }
}

// =====================================================================================
// GEMM geometry: 256x256 tile, BK=64, 512 threads (8 waves, 2x4), 128 KB LDS dbuf.
// Staging: per thread 8 x global_load_lds(16B); LDS rows are 128 B (64 bf16).
// Bank-conflict fix: both-sides XOR swizzle, byte_col ^= (row&7)<<4 (source-preswizzled
// global addr for the linear gl_lds write + swizzled ds_read col). Verified: each fixed
// 8-lane group hits all 8 bank-quads.
// Block mapping: bijective XCD chunking (grid%8==0), rt fastest -> expert e lives on
// XCD e; each (e,nt) B-panel stays L2-resident across rt tiles.
// =====================================================================================

__global__ __launch_bounds__(512, 2) void gemm1_kernel(
    const bf16* __restrict__ xbf, const bf16* __restrict__ w1t,
    const float* __restrict__ b1, const int* __restrict__ counts,
    const int* __restrict__ offsets, const int* __restrict__ tokl,
    bf16* __restrict__ hbuf, int Hc, int cbase) {
  int bid = blockIdx.x;
  int q = gridDim.x >> 3;
  int L = (bid & 7) * q + (bid >> 3);      // bijective XCD chunk swizzle
  int rt = L & 31;                          // T_TOK/256 = 32 row tiles (fastest)
  int g = L >> 5;
  int NT = Hc >> 8;                         // col tiles this chunk
  int nt = g % NT, e = g / NT;
  int cnt = counts[e];
  if (rt * 256 >= cnt) return;
  __shared__ __align__(16) bf16 sA[2][256 * 64];
  __shared__ __align__(16) bf16 sB[2][256 * 64];
  int tid = threadIdx.x, lane = tid & 63, w = tid >> 6;
  int ra = tid >> 3;                        // row within 64-row sweep
  int ko = (tid & 7) * 16;                  // byte-in-row (128 B rows)
  int kox = ko ^ ((ra & 7) << 4);           // pre-swizzled source byte-in-row
  int hoff = offsets[e];
  const char* gA[4];
  const char* gB[4];
#pragma unroll
  for (int s = 0; s < 4; ++s) {
    int r = imin(rt * 256 + ra + s * 64, cnt - 1);
    int t = tokl[e * T_TOK + r];
    gA[s] = (const char*)(xbf + (size_t)t * DM) + kox;
    int col = cbase + nt * 256 + ra + s * 64;
    gB[s] = (const char*)(w1t + ((size_t)e * HD + col) * DM) + kox;
  }
  char* la = (char*)sA;
  char* lb = (char*)sB;
  int dst = w * 1024;                       // wave-uniform LDS base (+lane*16 implicit)
  f32x4 acc[8][4];
#pragma unroll
  for (int i = 0; i < 8; ++i)
#pragma unroll
    for (int j = 0; j < 4; ++j) acc[i][j] = {0.f, 0.f, 0.f, 0.f};
  int mw = (w & 1) * 128, nw = (w >> 1) * 64;
  int swzr = (lane & 7) << 4;
  int colx = ((lane >> 4) * 16) ^ swzr;
  const char* pa0 = (const char*)sA + (mw + (lane & 15)) * 128 + colx;
  const char* pb0 = (const char*)sB + (nw + (lane & 15)) * 128 + colx;
  const char* pa1 = (const char*)sA + (mw + (lane & 15)) * 128 + (colx ^ 64);
  const char* pb1 = (const char*)sB + (nw + (lane & 15)) * 128 + (colx ^ 64);
  const int K = DM / 64;                    // 16 K-steps
  // prologue: stage k=0 into buf 0
#pragma unroll
  for (int s = 0; s < 4; ++s) gl_lds16(gA[s], la + s * 8192 + dst);
#pragma unroll
  for (int s = 0; s < 4; ++s) gl_lds16(gB[s], lb + s * 8192 + dst);
  for (int k = 0; k < K; ++k) {
    int nb = (k + 1) & 1;
    int kb = (k + 1 < K) ? (k + 1) * 128 : 0;  // last iter: dummy refetch of k=0
    char* lan = la + nb * 32768;
    char* lbn = lb + nb * 32768;
#pragma unroll
    for (int s = 0; s < 4; ++s) gl_lds16(gA[s] + kb, lan + s * 8192 + dst);
#pragma unroll
    for (int s = 0; s < 4; ++s) gl_lds16(gB[s] + kb, lbn + s * 8192 + dst);
    WAIT_VM8();      // own 8 loads of tile k landed
    RAW_BARRIER();   // everyone's landed
    int cb = (k & 1) * 32768;
    bf16x8 af[8], bfr[4];
    // k-half 0
#pragma unroll
    for (int i = 0; i < 8; ++i) af[i] = *(const bf16x8*)(pa0 + cb + i * 2048);
#pragma unroll
    for (int j = 0; j < 4; ++j) bfr[j] = *(const bf16x8*)(pb0 + cb + j * 2048);
#pragma unroll
    for (int i = 0; i < 8; ++i)
#pragma unroll
      for (int j = 0; j < 4; ++j)
        acc[i][j] = __builtin_amdgcn_mfma_f32_16x16x32_bf16(af[i], bfr[j], acc[i][j], 0, 0, 0);
    // k-half 1
#pragma unroll
    for (int i = 0; i < 8; ++i) af[i] = *(const bf16x8*)(pa1 + cb + i * 2048);
#pragma unroll
    for (int j = 0; j < 4; ++j) bfr[j] = *(const bf16x8*)(pb1 + cb + j * 2048);
#pragma unroll
    for (int i = 0; i < 8; ++i)
#pragma unroll
      for (int j = 0; j < 4; ++j)
        acc[i][j] = __builtin_amdgcn_mfma_f32_16x16x32_bf16(af[i], bfr[j], acc[i][j], 0, 0, 0);
    RAW_BARRIER();   // all reads of current buffer done before next overwrite
  }
  int colq = lane & 15, rowq = (lane >> 4) * 4;
  int hcol = nt * 256 + nw;
  float b1v[4];
#pragma unroll
  for (int j = 0; j < 4; ++j)
    b1v[j] = b1[(size_t)e * HD + cbase + hcol + j * 16 + colq];
#pragma unroll
  for (int i = 0; i < 8; ++i) {
#pragma unroll
    for (int r = 0; r < 4; ++r) {
      int grow = rt * 256 + mw + i * 16 + rowq + r;
      if (grow < cnt) {
        size_t hrow = (size_t)(hoff + grow) * Hc;
#pragma unroll
        for (int j = 0; j < 4; ++j) {
          float v = acc[i][j][r] + b1v[j];
          float gl = 0.5f * v * (1.f + erff(v * 0.70710678118654752f));
          hbuf[hrow + hcol + j * 16 + colq] = (bf16)gl;
        }
      }
    }
  }
}

__global__ __launch_bounds__(512, 2) void gemm2_kernel(
    const bf16* __restrict__ hbuf, const bf16* __restrict__ w2t,
    const float* __restrict__ b2, const int* __restrict__ counts,
    const int* __restrict__ offsets, const int* __restrict__ tokl,
    const float* __restrict__ wgt, float* __restrict__ out,
    int Hc, int cbase, float b2scale) {
  int bid = blockIdx.x;
  int q = gridDim.x >> 3;
  int L = (bid & 7) * q + (bid >> 3);
  int rt = L & 31;
  int g = L >> 5;
  const int NT = DM / 256;                  // 4 col tiles
  int nt = g % NT, e = g / NT;
  int cnt = counts[e];
  if (rt * 256 >= cnt) return;
  __shared__ __align__(16) bf16 sA[2][256 * 64];
  __shared__ __align__(16) bf16 sB[2][256 * 64];
  int tid = threadIdx.x, lane = tid & 63, w = tid >> 6;
  int ra = tid >> 3;
  int ko = (tid & 7) * 16;
  int kox = ko ^ ((ra & 7) << 4);
  int hoff = offsets[e];
  const char* gA[4];
  const char* gB[4];
#pragma unroll
  for (int s = 0; s < 4; ++s) {
    int r = imin(rt * 256 + ra + s * 64, cnt - 1);
    gA[s] = (const char*)(hbuf + (size_t)(hoff + r) * Hc) + kox;
    int col = nt * 256 + ra + s * 64;
    gB[s] = (const char*)(w2t + ((size_t)e * DM + col) * HD + cbase) + kox;
  }
  char* la = (char*)sA;
  char* lb = (char*)sB;
  int dst = w * 1024;
  f32x4 acc[8][4];
#pragma unroll
  for (int i = 0; i < 8; ++i)
#pragma unroll
    for (int j = 0; j < 4; ++j) acc[i][j] = {0.f, 0.f, 0.f, 0.f};
  int mw = (w & 1) * 128, nw = (w >> 1) * 64;
  int swzr = (lane & 7) << 4;
  int colx = ((lane >> 4) * 16) ^ swzr;
  const char* pa0 = (const char*)sA + (mw + (lane & 15)) * 128 + colx;
  const char* pb0 = (const char*)sB + (nw + (lane & 15)) * 128 + colx;
  const char* pa1 = (const char*)sA + (mw + (lane & 15)) * 128 + (colx ^ 64);
  const char* pb1 = (const char*)sB + (nw + (lane & 15)) * 128 + (colx ^ 64);
  const int K = Hc / 64;
  // prologue
#pragma unroll
  for (int s = 0; s < 4; ++s) gl_lds16(gA[s], la + s * 8192 + dst);
#pragma unroll
  for (int s = 0; s < 4; ++s) gl_lds16(gB[s], lb + s * 8192 + dst);
  for (int k = 0; k < K; ++k) {
    int nb = (k + 1) & 1;
    int kb = (k + 1 < K) ? (k + 1) * 128 : 0;
    char* lan = la + nb * 32768;
    char* lbn = lb + nb * 32768;
#pragma unroll
    for (int s = 0; s < 4; ++s) gl_lds16(gA[s] + kb, lan + s * 8192 + dst);
#pragma unroll
    for (int s = 0; s < 4; ++s) gl_lds16(gB[s] + kb, lbn + s * 8192 + dst);
    WAIT_VM8();
    RAW_BARRIER();
    int cb = (k & 1) * 32768;
    bf16x8 af[8], bfr[4];
#pragma unroll
    for (int i = 0; i < 8; ++i) af[i] = *(const bf16x8*)(pa0 + cb + i * 2048);
#pragma unroll
    for (int j = 0; j < 4; ++j) bfr[j] = *(const bf16x8*)(pb0 + cb + j * 2048);
#pragma unroll
    for (int i = 0; i < 8; ++i)
#pragma unroll
      for (int j = 0; j < 4; ++j)
        acc[i][j] = __builtin_amdgcn_mfma_f32_16x16x32_bf16(af[i], bfr[j], acc[i][j], 0, 0, 0);
#pragma unroll
    for (int i = 0; i < 8; ++i) af[i] = *(const bf16x8*)(pa1 + cb + i * 2048);
#pragma unroll
    for (int j = 0; j < 4; ++j) bfr[j] = *(const bf16x8*)(pb1 + cb + j * 2048);
#pragma unroll
    for (int i = 0; i < 8; ++i)
#pragma unroll
      for (int j = 0; j < 4; ++j)
        acc[i][j] = __builtin_amdgcn_mfma_f32_16x16x32_bf16(af[i], bfr[j], acc[i][j], 0, 0, 0);
    RAW_BARRIER();
  }
  int colq = lane & 15, rowq = (lane >> 4) * 4;
  float b2v[4];
#pragma unroll
  for (int j = 0; j < 4; ++j)
    b2v[j] = b2[(size_t)e * DM + nt * 256 + nw + j * 16 + colq] * b2scale;
#pragma unroll
  for (int i = 0; i < 8; ++i) {
#pragma unroll
    for (int r = 0; r < 4; ++r) {
      int grow = rt * 256 + mw + i * 16 + rowq + r;
      if (grow < cnt) {
        float wv = wgt[e * T_TOK + grow];
        int tk = tokl[e * T_TOK + grow];
        float* orow = out + (size_t)tk * DM + nt * 256 + nw;
#pragma unroll
        for (int j = 0; j < 4; ++j)
          atomicAdd(orow + j * 16 + colq, wv * (acc[i][j][r] + b2v[j]));
      }
    }
  }
}

extern "C" void kernel_launch(void* const* d_in, const int* in_sizes, int n_in,
                              void* d_out, int out_size, void* d_ws, size_t ws_size,
                              hipStream_t stream) {
  const float* x  = (const float*)d_in[0];
  const float* Wg = (const float*)d_in[1];
  const float* bg = (const float*)d_in[2];
  const float* W1 = (const float*)d_in[3];
  const float* b1 = (const float*)d_in[4];
  const float* W2 = (const float*)d_in[5];
  const float* b2 = (const float*)d_in[6];
  float* out = (float*)d_out;

  char* ws = (char*)d_ws;
  size_t off = 0;
  auto alloc = [&](size_t bytes) -> void* {
    void* p = ws + off;
    off = (off + bytes + 255) & ~(size_t)255;
    return p;
  };
  int*   counts  = (int*)alloc(NE * 4);
  int*   offsets = (int*)alloc((NE + 1) * 4);
  int*   tokl    = (int*)alloc((size_t)NE * T_TOK * 4);
  float* wgt     = (float*)alloc((size_t)NE * T_TOK * 4);
  bf16*  xbf     = (bf16*)alloc((size_t)T_TOK * DM * 2);
  bf16*  w1t     = (bf16*)alloc((size_t)NE * HD * DM * 2);
  bf16*  w2t     = (bf16*)alloc((size_t)NE * DM * HD * 2);
  size_t remain = ws_size > off ? ws_size - off : 0;
  int Hc = HD;
  while (Hc > 256 && (size_t)2 * T_TOK * Hc * 2 > remain) Hc >>= 1;  // h rows total = 2*T
  bf16* hbuf = (bf16*)alloc((size_t)2 * T_TOK * Hc * 2);

  zero_kernel<<<4096, 256, 0, stream>>>(out, counts);
  transpose_cvt_kernel<<<dim3(HD / 64, DM / 64, NE), 256, 0, stream>>>(W1, w1t, DM, HD);
  transpose_cvt_kernel<<<dim3(DM / 64, HD / 64, NE), 256, 0, stream>>>(W2, w2t, HD, DM);
  gating_kernel<<<T_TOK / 4, 256, 0, stream>>>(x, Wg, bg, counts, tokl, wgt, xbf);
  scan_kernel<<<1, 64, 0, stream>>>(counts, offsets);

  int nchunk = HD / Hc;
  for (int c = 0; c < nchunk; ++c) {
    gemm1_kernel<<<NE * (Hc / 256) * (T_TOK / 256), 512, 0, stream>>>(
        xbf, w1t, b1, counts, offsets, tokl, hbuf, Hc, c * Hc);
    gemm2_kernel<<<NE * (DM / 256) * (T_TOK / 256), 512, 0, stream>>>(
        hbuf, w2t, b2, counts, offsets, tokl, wgt, out, Hc, c * Hc, c == 0 ? 1.f : 0.f);
  }
}

// Round 3
// 1111.549 us; speedup vs baseline: 1.0395x; 1.0395x over previous
//
#include <hip/hip_runtime.h>
#include <hip/hip_bf16.h>
#include <math.h>

// Problem constants (B=4, S=2048 -> T=8192 tokens)
#define T_TOK 8192
#define DM    1024
#define NE    8
#define HD    4096

typedef __bf16 bf16;
typedef __attribute__((ext_vector_type(8))) __bf16 bf16x8;
typedef __attribute__((ext_vector_type(4))) float  f32x4;

__device__ __forceinline__ void gl_lds16(const void* g, void* l) {
  __builtin_amdgcn_global_load_lds((const __attribute__((address_space(1))) void*)g,
                                   (__attribute__((address_space(3))) void*)l, 16, 0, 0);
}

#define RAW_BARRIER() asm volatile("s_barrier" ::: "memory")
#define VMCNT4()      asm volatile("s_waitcnt vmcnt(4)" ::: "memory")
#define LGKM0()       asm volatile("s_waitcnt lgkmcnt(0)" ::: "memory")

__device__ __forceinline__ int imin(int a, int b) { return a < b ? a : b; }

// ---------------- zero out + counts ----------------
__global__ void zero_kernel(float* __restrict__ out, int* __restrict__ counts) {
  size_t stride = (size_t)gridDim.x * blockDim.x;
  size_t n4 = (size_t)T_TOK * DM / 4;
  for (size_t i = (size_t)blockIdx.x * blockDim.x + threadIdx.x; i < n4; i += stride) {
    float4 z = {0.f, 0.f, 0.f, 0.f};
    ((float4*)out)[i] = z;
  }
  if (blockIdx.x == 0 && threadIdx.x < NE) counts[threadIdx.x] = 0;
}

// ---------------- transpose + cvt: in [e][R][C] fp32 -> out [e][C][R] bf16 ----------------
__global__ void transpose_cvt_kernel(const float* __restrict__ in, bf16* __restrict__ out,
                                     int R, int C) {
  __shared__ float tile[64][65];
  int e = blockIdx.z;
  int c0 = blockIdx.x * 64, r0 = blockIdx.y * 64;
  int tid = threadIdx.x;
  int lr = tid >> 2, lc = (tid & 3) * 16;
  const float* src = in + ((size_t)e * R + r0 + lr) * C + c0 + lc;
#pragma unroll
  for (int q = 0; q < 4; ++q) {
    float4 v = *(const float4*)(src + q * 4);
    tile[lr][lc + q * 4 + 0] = v.x;
    tile[lr][lc + q * 4 + 1] = v.y;
    tile[lr][lc + q * 4 + 2] = v.z;
    tile[lr][lc + q * 4 + 3] = v.w;
  }
  __syncthreads();
  int oc = tid >> 3;      // 0..31
  int rchunk = tid & 7;   // 0..7
#pragma unroll
  for (int q = 0; q < 2; ++q) {
    int ocq = oc + q * 32;
    bf16x8 o;
#pragma unroll
    for (int k = 0; k < 8; ++k) o[k] = (bf16)tile[rchunk * 8 + k][ocq];
    *(bf16x8*)(out + ((size_t)e * C + c0 + ocq) * R + r0 + rchunk * 8) = o;
  }
}

// ---------------- gating: logits (double), softmax, top-2, compaction + x->bf16 ----------------
__global__ void gating_kernel(const float* __restrict__ x, const float* __restrict__ Wg,
                              const float* __restrict__ bg, int* __restrict__ counts,
                              int* __restrict__ tokl, float* __restrict__ wgt,
                              bf16* __restrict__ xb) {
  int t = blockIdx.x * 4 + (threadIdx.x >> 6);
  int lane = threadIdx.x & 63;
  if (t >= T_TOK) return;
  double acc[NE];
#pragma unroll
  for (int e = 0; e < NE; ++e) acc[e] = 0.0;
  const float* xr = x + (size_t)t * DM;
  bf16* xbr = xb + (size_t)t * DM;
  for (int d = lane; d < DM; d += 64) {
    float xv = xr[d];
    xbr[d] = (bf16)xv;   // fused fp32->bf16 conversion
#pragma unroll
    for (int e = 0; e < NE; ++e) acc[e] += (double)xv * (double)Wg[d * NE + e];
  }
#pragma unroll
  for (int e = 0; e < NE; ++e)
    for (int o = 32; o > 0; o >>= 1) acc[e] += __shfl_down(acc[e], o, 64);
  if (lane == 0) {
    float l[NE], w[NE];
    float m = -1e30f;
#pragma unroll
    for (int e = 0; e < NE; ++e) { l[e] = (float)acc[e] + bg[e]; m = fmaxf(m, l[e]); }
    float s = 0.f;
#pragma unroll
    for (int e = 0; e < NE; ++e) { w[e] = expf(l[e] - m); s += w[e]; }
    float inv = 1.f / s;
#pragma unroll
    for (int e = 0; e < NE; ++e) w[e] *= inv;
    int e1 = 0; float v1 = w[0];
#pragma unroll
    for (int e = 1; e < NE; ++e) if (w[e] > v1) { v1 = w[e]; e1 = e; }
    int e2 = -1; float v2 = -1.f;
#pragma unroll
    for (int e = 0; e < NE; ++e) if (e != e1 && w[e] > v2) { v2 = w[e]; e2 = e; }
    int s1 = atomicAdd(&counts[e1], 1);
    tokl[e1 * T_TOK + s1] = t; wgt[e1 * T_TOK + s1] = v1;
    int s2 = atomicAdd(&counts[e2], 1);
    tokl[e2 * T_TOK + s2] = t; wgt[e2 * T_TOK + s2] = v2;
  }
}

// ---------------- scan ----------------
__global__ void scan_kernel(const int* __restrict__ counts, int* __restrict__ offsets) {
  if (threadIdx.x == 0 && blockIdx.x == 0) {
    int s = 0;
#pragma unroll
    for (int e = 0; e < NE; ++e) { offsets[e] = s; s += counts[e]; }
    offsets[NE] = s;
  }
}

// =====================================================================================
// 256x256 tile, BK=64, 512 thr (8 waves, wm=w&1 wn=w>>1), 128 KB LDS dbuf.
// 4-phase counted-vmcnt schedule, phase order (ih,jh) = (0,0),(0,1),(1,0),(1,1):
// single af[8] reused across jh (register fix: ~210 VGPR, no spill under (512,2)).
// Per-tile prefetch issue slots: P0->Ah0, P1->Bh0, P2->Bh1, P3->Ah1 (order matters).
// vmcnt(4) at ends of P0/P1/P3: each half-tile has >=3 phases issue->read cover;
// counter never drains below 4. Cross-wave ordering: own vmcnt -> barrier -> read.
// T2 XOR swizzle (pre-swizzled gl_lds source + swizzled ds_read col): 0 conflicts.
// XCD-bijective block map: expert e pinned to XCD e; B panels L2-resident.
// =====================================================================================

#define LDA_F(IH, CB) \
  _Pragma("unroll") for (int kh = 0; kh < 2; ++kh) \
  _Pragma("unroll") for (int i = 0; i < 4; ++i) \
    af[kh*4+i] = *(const bf16x8*)(Ab + (CB) + (128*(IH) + 64*wm + 16*i + lf) * 128 + (colx ^ (kh*64)));

#define LDB_F(JH, CB) \
  _Pragma("unroll") for (int kh = 0; kh < 2; ++kh) \
  _Pragma("unroll") for (int j = 0; j < 2; ++j) \
    bfr[kh*2+j] = *(const bf16x8*)(Bb + (CB) + (128*(JH) + 32*wn + 16*j + lf) * 128 + (colx ^ (kh*64)));

#define MM_F(IH, JH) \
  _Pragma("unroll") for (int kh = 0; kh < 2; ++kh) \
  _Pragma("unroll") for (int i = 0; i < 4; ++i) \
  _Pragma("unroll") for (int j = 0; j < 2; ++j) \
    acc[IH][JH][i][j] = __builtin_amdgcn_mfma_f32_16x16x32_bf16(af[kh*4+i], bfr[kh*2+j], acc[IH][JH][i][j], 0, 0, 0);

#define ISSUE_A(H, NBO, KB) do { \
    gl_lds16(gA[2*(H)] + (KB), Al + (NBO) + (H)*16384 + dst); \
    gl_lds16(gA[2*(H)+1] + (KB), Al + (NBO) + (H)*16384 + 8192 + dst); \
  } while (0)
#define ISSUE_B(H, NBO, KB) do { \
    gl_lds16(gB[2*(H)] + (KB), Bl + (NBO) + (H)*16384 + dst); \
    gl_lds16(gB[2*(H)+1] + (KB), Bl + (NBO) + (H)*16384 + 8192 + dst); \
  } while (0)

#define PH_TAIL(IH, JH) \
    RAW_BARRIER(); \
    LGKM0(); __builtin_amdgcn_sched_barrier(0); \
    __builtin_amdgcn_s_setprio(1); \
    MM_F(IH, JH); \
    __builtin_amdgcn_s_setprio(0);

#define KTILE_BODY(CB, NBO, KB) \
    /* P0: (0,0) reads Ah0,Bh0 */ \
    LDA_F(0, CB); \
    LDB_F(0, CB); \
    ISSUE_A(0, NBO, KB); \
    PH_TAIL(0, 0) \
    VMCNT4(); \
    RAW_BARRIER(); \
    /* P1: (0,1) reads Bh1 */ \
    LDB_F(1, CB); \
    ISSUE_B(0, NBO, KB); \
    PH_TAIL(0, 1) \
    VMCNT4(); \
    RAW_BARRIER(); \
    /* P2: (1,0) reads Ah1, Bh0(again) */ \
    LDA_F(1, CB); \
    LDB_F(0, CB); \
    ISSUE_B(1, NBO, KB); \
    PH_TAIL(1, 0) \
    RAW_BARRIER(); \
    /* P3: (1,1) reads Bh1(again) */ \
    LDB_F(1, CB); \
    ISSUE_A(1, NBO, KB); \
    PH_TAIL(1, 1) \
    VMCNT4(); \
    RAW_BARRIER();

__global__ __launch_bounds__(512, 2) void gemm1_kernel(
    const bf16* __restrict__ xbf, const bf16* __restrict__ w1t,
    const float* __restrict__ b1, const int* __restrict__ counts,
    const int* __restrict__ offsets, const int* __restrict__ tokl,
    bf16* __restrict__ hbuf, int Hc, int cbase) {
  int bid = blockIdx.x;
  int q = gridDim.x >> 3;
  int L = (bid & 7) * q + (bid >> 3);
  int rt = L & 31;
  int g = L >> 5;
  int NT = Hc >> 8;
  int nt = g % NT, e = g / NT;
  int cnt = counts[e];
  if (rt * 256 >= cnt) return;
  __shared__ __align__(16) bf16 sA[2][256 * 64];
  __shared__ __align__(16) bf16 sB[2][256 * 64];
  int tid = threadIdx.x, lane = tid & 63, w = tid >> 6;
  int wm = w & 1, wn = w >> 1;
  int lf = lane & 15;
  int colx = ((lane >> 4) * 16) ^ ((lane & 7) << 4);
  int ra = tid >> 3;
  int ko = (tid & 7) * 16;
  int kox = ko ^ ((ra & 7) << 4);
  int dst = w * 1024;
  int hoff = offsets[e];
  const char* gA[4];
  const char* gB[4];
#pragma unroll
  for (int s = 0; s < 4; ++s) {
    int r = imin(rt * 256 + ra + s * 64, cnt - 1);
    int t = tokl[e * T_TOK + r];
    gA[s] = (const char*)(xbf + (size_t)t * DM) + kox;
    int col = cbase + nt * 256 + ra + s * 64;
    gB[s] = (const char*)(w1t + ((size_t)e * HD + col) * DM) + kox;
  }
  char* Al = (char*)sA;
  char* Bl = (char*)sB;
  const char* Ab = (const char*)sA;
  const char* Bb = (const char*)sB;
  f32x4 acc[2][2][4][2];
#pragma unroll
  for (int ih = 0; ih < 2; ++ih)
#pragma unroll
    for (int jh = 0; jh < 2; ++jh)
#pragma unroll
      for (int i = 0; i < 4; ++i)
#pragma unroll
        for (int j = 0; j < 2; ++j) acc[ih][jh][i][j] = {0.f, 0.f, 0.f, 0.f};
  bf16x8 af[8], bfr[4];
  const int K = DM / 64;  // 16
  // prologue: stage tile 0, issue order Ah0, Bh0, Bh1, Ah1 (matches loop slots)
  ISSUE_A(0, 0, 0); ISSUE_B(0, 0, 0); ISSUE_B(1, 0, 0); ISSUE_A(1, 0, 0);
  VMCNT4();
  RAW_BARRIER();
  for (int k = 0; k < K; ++k) {
    int cb = (k & 1) * 32768;
    int nbo = ((k + 1) & 1) * 32768;
    int kb = (k + 1 < K) ? (k + 1) * 128 : 0;  // last iter: dummy refetch
    KTILE_BODY(cb, nbo, kb)
  }
  // epilogue
  int colq = lane & 15, rowq = (lane >> 4) * 4;
  size_t ebase = (size_t)e * HD + cbase + nt * 256;
  float b1v[2][2];
#pragma unroll
  for (int jh = 0; jh < 2; ++jh)
#pragma unroll
    for (int j = 0; j < 2; ++j)
      b1v[jh][j] = b1[ebase + 128 * jh + 32 * wn + 16 * j + colq];
#pragma unroll
  for (int ih = 0; ih < 2; ++ih) {
#pragma unroll
    for (int i = 0; i < 4; ++i) {
#pragma unroll
      for (int r = 0; r < 4; ++r) {
        int grow = rt * 256 + 128 * ih + 64 * wm + 16 * i + rowq + r;
        if (grow < cnt) {
          size_t hrow = (size_t)(hoff + grow) * Hc + nt * 256;
#pragma unroll
          for (int jh = 0; jh < 2; ++jh) {
#pragma unroll
            for (int j = 0; j < 2; ++j) {
              float v = acc[ih][jh][i][j][r] + b1v[jh][j];
              float gl = 0.5f * v * (1.f + erff(v * 0.70710678118654752f));
              hbuf[hrow + 128 * jh + 32 * wn + 16 * j + colq] = (bf16)gl;
            }
          }
        }
      }
    }
  }
}

__global__ __launch_bounds__(512, 2) void gemm2_kernel(
    const bf16* __restrict__ hbuf, const bf16* __restrict__ w2t,
    const float* __restrict__ b2, const int* __restrict__ counts,
    const int* __restrict__ offsets, const int* __restrict__ tokl,
    const float* __restrict__ wgt, float* __restrict__ out,
    int Hc, int cbase, float b2scale) {
  int bid = blockIdx.x;
  int q = gridDim.x >> 3;
  int L = (bid & 7) * q + (bid >> 3);
  int rt = L & 31;
  int g = L >> 5;
  const int NT = DM / 256;  // 4
  int nt = g % NT, e = g / NT;
  int cnt = counts[e];
  if (rt * 256 >= cnt) return;
  __shared__ __align__(16) bf16 sA[2][256 * 64];
  __shared__ __align__(16) bf16 sB[2][256 * 64];
  int tid = threadIdx.x, lane = tid & 63, w = tid >> 6;
  int wm = w & 1, wn = w >> 1;
  int lf = lane & 15;
  int colx = ((lane >> 4) * 16) ^ ((lane & 7) << 4);
  int ra = tid >> 3;
  int ko = (tid & 7) * 16;
  int kox = ko ^ ((ra & 7) << 4);
  int dst = w * 1024;
  int hoff = offsets[e];
  const char* gA[4];
  const char* gB[4];
#pragma unroll
  for (int s = 0; s < 4; ++s) {
    int r = imin(rt * 256 + ra + s * 64, cnt - 1);
    gA[s] = (const char*)(hbuf + (size_t)(hoff + r) * Hc) + kox;
    int col = nt * 256 + ra + s * 64;
    gB[s] = (const char*)(w2t + ((size_t)e * DM + col) * HD + cbase) + kox;
  }
  char* Al = (char*)sA;
  char* Bl = (char*)sB;
  const char* Ab = (const char*)sA;
  const char* Bb = (const char*)sB;
  f32x4 acc[2][2][4][2];
#pragma unroll
  for (int ih = 0; ih < 2; ++ih)
#pragma unroll
    for (int jh = 0; jh < 2; ++jh)
#pragma unroll
      for (int i = 0; i < 4; ++i)
#pragma unroll
        for (int j = 0; j < 2; ++j) acc[ih][jh][i][j] = {0.f, 0.f, 0.f, 0.f};
  bf16x8 af[8], bfr[4];
  const int K = Hc / 64;
  ISSUE_A(0, 0, 0); ISSUE_B(0, 0, 0); ISSUE_B(1, 0, 0); ISSUE_A(1, 0, 0);
  VMCNT4();
  RAW_BARRIER();
  for (int k = 0; k < K; ++k) {
    int cb = (k & 1) * 32768;
    int nbo = ((k + 1) & 1) * 32768;
    int kb = (k + 1 < K) ? (k + 1) * 128 : 0;
    KTILE_BODY(cb, nbo, kb)
  }
  int colq = lane & 15, rowq = (lane >> 4) * 4;
  float b2v[2][2];
#pragma unroll
  for (int jh = 0; jh < 2; ++jh)
#pragma unroll
    for (int j = 0; j < 2; ++j)
      b2v[jh][j] = b2[(size_t)e * DM + nt * 256 + 128 * jh + 32 * wn + 16 * j + colq] * b2scale;
#pragma unroll
  for (int ih = 0; ih < 2; ++ih) {
#pragma unroll
    for (int i = 0; i < 4; ++i) {
#pragma unroll
      for (int r = 0; r < 4; ++r) {
        int grow = rt * 256 + 128 * ih + 64 * wm + 16 * i + rowq + r;
        if (grow < cnt) {
          float wv = wgt[e * T_TOK + grow];
          int tk = tokl[e * T_TOK + grow];
          float* orow = out + (size_t)tk * DM + nt * 256;
#pragma unroll
          for (int jh = 0; jh < 2; ++jh) {
#pragma unroll
            for (int j = 0; j < 2; ++j)
              atomicAdd(orow + 128 * jh + 32 * wn + 16 * j + colq,
                        wv * (acc[ih][jh][i][j][r] + b2v[jh][j]));
          }
        }
      }
    }
  }
}

extern "C" void kernel_launch(void* const* d_in, const int* in_sizes, int n_in,
                              void* d_out, int out_size, void* d_ws, size_t ws_size,
                              hipStream_t stream) {
  const float* x  = (const float*)d_in[0];
  const float* Wg = (const float*)d_in[1];
  const float* bg = (const float*)d_in[2];
  const float* W1 = (const float*)d_in[3];
  const float* b1 = (const float*)d_in[4];
  const float* W2 = (const float*)d_in[5];
  const float* b2 = (const float*)d_in[6];
  float* out = (float*)d_out;

  char* ws = (char*)d_ws;
  size_t off = 0;
  auto alloc = [&](size_t bytes) -> void* {
    void* p = ws + off;
    off = (off + bytes + 255) & ~(size_t)255;
    return p;
  };
  int*   counts  = (int*)alloc(NE * 4);
  int*   offsets = (int*)alloc((NE + 1) * 4);
  int*   tokl    = (int*)alloc((size_t)NE * T_TOK * 4);
  float* wgt     = (float*)alloc((size_t)NE * T_TOK * 4);
  bf16*  xbf     = (bf16*)alloc((size_t)T_TOK * DM * 2);
  bf16*  w1t     = (bf16*)alloc((size_t)NE * HD * DM * 2);
  bf16*  w2t     = (bf16*)alloc((size_t)NE * DM * HD * 2);
  size_t remain = ws_size > off ? ws_size - off : 0;
  int Hc = HD;
  while (Hc > 256 && (size_t)2 * T_TOK * Hc * 2 > remain) Hc >>= 1;  // h rows total = 2*T
  bf16* hbuf = (bf16*)alloc((size_t)2 * T_TOK * Hc * 2);

  zero_kernel<<<4096, 256, 0, stream>>>(out, counts);
  transpose_cvt_kernel<<<dim3(HD / 64, DM / 64, NE), 256, 0, stream>>>(W1, w1t, DM, HD);
  transpose_cvt_kernel<<<dim3(DM / 64, HD / 64, NE), 256, 0, stream>>>(W2, w2t, HD, DM);
  gating_kernel<<<T_TOK / 4, 256, 0, stream>>>(x, Wg, bg, counts, tokl, wgt, xbf);
  scan_kernel<<<1, 64, 0, stream>>>(counts, offsets);

  int nchunk = HD / Hc;
  for (int c = 0; c < nchunk; ++c) {
    gemm1_kernel<<<NE * (Hc / 256) * (T_TOK / 256), 512, 0, stream>>>(
        xbf, w1t, b1, counts, offsets, tokl, hbuf, Hc, c * Hc);
    gemm2_kernel<<<NE * (DM / 256) * (T_TOK / 256), 512, 0, stream>>>(
        hbuf, w2t, b2, counts, offsets, tokl, wgt, out, Hc, c * Hc, c == 0 ? 1.f : 0.f);
  }
}

// Round 5
// 1102.753 us; speedup vs baseline: 1.0478x; 1.0080x over previous
//
#include <hip/hip_runtime.h>
#include <hip/hip_bf16.h>
#include <math.h>

// Problem constants (B=4, S=2048 -> T=8192 tokens)
#define T_TOK 8192
#define DM    1024
#define NE    8
#define HD    4096

typedef __bf16 bf16;
typedef __attribute__((ext_vector_type(8))) __bf16 bf16x8;
typedef __attribute__((ext_vector_type(4))) float  f32x4;

__device__ __forceinline__ void gl_lds16(const void* g, void* l) {
  __builtin_amdgcn_global_load_lds((const __attribute__((address_space(1))) void*)g,
                                   (__attribute__((address_space(3))) void*)l, 16, 0, 0);
}

#define RAW_BARRIER() asm volatile("s_barrier" ::: "memory")
#define VMCNT6()      asm volatile("s_waitcnt vmcnt(6)" ::: "memory")
#define VMCNT2()      asm volatile("s_waitcnt vmcnt(2)" ::: "memory")

__device__ __forceinline__ int imin(int a, int b) { return a < b ? a : b; }

// ---------------- zero out + counts ----------------
__global__ void zero_kernel(float* __restrict__ out, int* __restrict__ counts) {
  size_t stride = (size_t)gridDim.x * blockDim.x;
  size_t n4 = (size_t)T_TOK * DM / 4;
  for (size_t i = (size_t)blockIdx.x * blockDim.x + threadIdx.x; i < n4; i += stride) {
    float4 z = {0.f, 0.f, 0.f, 0.f};
    ((float4*)out)[i] = z;
  }
  if (blockIdx.x == 0 && threadIdx.x < NE) counts[threadIdx.x] = 0;
}

// ---------------- transpose + cvt: in [e][R][C] fp32 -> out [e][C][R] bf16 ----------------
__global__ void transpose_cvt_kernel(const float* __restrict__ in, bf16* __restrict__ out,
                                     int R, int C) {
  __shared__ float tile[64][65];
  int e = blockIdx.z;
  int c0 = blockIdx.x * 64, r0 = blockIdx.y * 64;
  int tid = threadIdx.x;
  int lr = tid >> 2, lc = (tid & 3) * 16;
  const float* src = in + ((size_t)e * R + r0 + lr) * C + c0 + lc;
#pragma unroll
  for (int q = 0; q < 4; ++q) {
    float4 v = *(const float4*)(src + q * 4);
    tile[lr][lc + q * 4 + 0] = v.x;
    tile[lr][lc + q * 4 + 1] = v.y;
    tile[lr][lc + q * 4 + 2] = v.z;
    tile[lr][lc + q * 4 + 3] = v.w;
  }
  __syncthreads();
  int oc = tid >> 3;      // 0..31
  int rchunk = tid & 7;   // 0..7
#pragma unroll
  for (int q = 0; q < 2; ++q) {
    int ocq = oc + q * 32;
    bf16x8 o;
#pragma unroll
    for (int k = 0; k < 8; ++k) o[k] = (bf16)tile[rchunk * 8 + k][ocq];
    *(bf16x8*)(out + ((size_t)e * C + c0 + ocq) * R + r0 + rchunk * 8) = o;
  }
}

// ---------------- gating: logits (double), softmax, top-2, compaction + x->bf16 ----------------
__global__ void gating_kernel(const float* __restrict__ x, const float* __restrict__ Wg,
                              const float* __restrict__ bg, int* __restrict__ counts,
                              int* __restrict__ tokl, float* __restrict__ wgt,
                              bf16* __restrict__ xb) {
  int t = blockIdx.x * 4 + (threadIdx.x >> 6);
  int lane = threadIdx.x & 63;
  if (t >= T_TOK) return;
  double acc[NE];
#pragma unroll
  for (int e = 0; e < NE; ++e) acc[e] = 0.0;
  const float* xr = x + (size_t)t * DM;
  bf16* xbr = xb + (size_t)t * DM;
  for (int d = lane; d < DM; d += 64) {
    float xv = xr[d];
    xbr[d] = (bf16)xv;   // fused fp32->bf16 conversion
#pragma unroll
    for (int e = 0; e < NE; ++e) acc[e] += (double)xv * (double)Wg[d * NE + e];
  }
#pragma unroll
  for (int e = 0; e < NE; ++e)
    for (int o = 32; o > 0; o >>= 1) acc[e] += __shfl_down(acc[e], o, 64);
  if (lane == 0) {
    float l[NE], w[NE];
    float m = -1e30f;
#pragma unroll
    for (int e = 0; e < NE; ++e) { l[e] = (float)acc[e] + bg[e]; m = fmaxf(m, l[e]); }
    float s = 0.f;
#pragma unroll
    for (int e = 0; e < NE; ++e) { w[e] = expf(l[e] - m); s += w[e]; }
    float inv = 1.f / s;
#pragma unroll
    for (int e = 0; e < NE; ++e) w[e] *= inv;
    int e1 = 0; float v1 = w[0];
#pragma unroll
    for (int e = 1; e < NE; ++e) if (w[e] > v1) { v1 = w[e]; e1 = e; }
    int e2 = -1; float v2 = -1.f;
#pragma unroll
    for (int e = 0; e < NE; ++e) if (e != e1 && w[e] > v2) { v2 = w[e]; e2 = e; }
    int s1 = atomicAdd(&counts[e1], 1);
    tokl[e1 * T_TOK + s1] = t; wgt[e1 * T_TOK + s1] = v1;
    int s2 = atomicAdd(&counts[e2], 1);
    tokl[e2 * T_TOK + s2] = t; wgt[e2 * T_TOK + s2] = v2;
  }
}

// ---------------- scan ----------------
__global__ void scan_kernel(const int* __restrict__ counts, int* __restrict__ offsets) {
  if (threadIdx.x == 0 && blockIdx.x == 0) {
    int s = 0;
#pragma unroll
    for (int e = 0; e < NE; ++e) { offsets[e] = s; s += counts[e]; }
    offsets[NE] = s;
  }
}

// =====================================================================================
// 256x256 tile, BK=64, 512 thr (8 waves, wm=w&1 wn=w>>1), 128 KB LDS dbuf.
// 2-PHASE dual-barrier pipeline, compiler-scheduled LDS reads (no lgkm pinning):
//   PA: ds_read af(ih0)+bfr0+bfr1; issue prefetch {Ah0,Bh0,Bh1}; vmcnt(6); BAR;
//       MFMA (0,0)+(0,1)  [compiler interleaves lgkmcnt(N) waits under MFMAs]; BAR;
//   PB: ds_read af(ih1); issue {Ah1}; vmcnt(2); BAR; MFMA (1,0)+(1,1); BAR;
// Ledger: staging for tile t's {A0,B0,B1} drained by t-1 PB's vmcnt(2) (1 phase +
// barrier before first read); {A1} by PA's vmcnt(6). Counter never below 2. Every LDS
// region is MFMA-consumed before its phase's BAR2 and overwritten >=2 barriers later.
// Registers: af 32 + bfr 32 + addr ~ 110 VGPR + 128 AGPR < 256 (no spill).
// T2 XOR swizzle (pre-swizzled gl_lds source + swizzled ds_read col): 0 conflicts.
// XCD-bijective block map: expert e pinned to XCD e; B panels L2-resident.
// =====================================================================================

#define LDA_F(IH, CB) \
  _Pragma("unroll") for (int kh = 0; kh < 2; ++kh) \
  _Pragma("unroll") for (int i = 0; i < 4; ++i) \
    af[kh*4+i] = *(const bf16x8*)(Ab + (CB) + (128*(IH) + 64*wm + 16*i + lf) * 128 + (colx ^ (kh*64)));

#define LDB_F(BF, JH, CB) \
  _Pragma("unroll") for (int kh = 0; kh < 2; ++kh) \
  _Pragma("unroll") for (int j = 0; j < 2; ++j) \
    BF[kh*2+j] = *(const bf16x8*)(Bb + (CB) + (128*(JH) + 32*wn + 16*j + lf) * 128 + (colx ^ (kh*64)));

#define MM_F(IH, JH, BF) \
  _Pragma("unroll") for (int kh = 0; kh < 2; ++kh) \
  _Pragma("unroll") for (int i = 0; i < 4; ++i) \
  _Pragma("unroll") for (int j = 0; j < 2; ++j) \
    acc[IH][JH][i][j] = __builtin_amdgcn_mfma_f32_16x16x32_bf16(af[kh*4+i], BF[kh*2+j], acc[IH][JH][i][j], 0, 0, 0);

#define ISSUE_A(H, NBO, KB) do { \
    gl_lds16(gA[2*(H)] + (KB), Al + (NBO) + (H)*16384 + dst); \
    gl_lds16(gA[2*(H)+1] + (KB), Al + (NBO) + (H)*16384 + 8192 + dst); \
  } while (0)
#define ISSUE_B(H, NBO, KB) do { \
    gl_lds16(gB[2*(H)] + (KB), Bl + (NBO) + (H)*16384 + dst); \
    gl_lds16(gB[2*(H)+1] + (KB), Bl + (NBO) + (H)*16384 + 8192 + dst); \
  } while (0)

#define KTILE_BODY(CB, NBO, KB) \
    /* Phase A: ih = 0 */ \
    LDA_F(0, CB); \
    LDB_F(bfr0, 0, CB); \
    LDB_F(bfr1, 1, CB); \
    ISSUE_A(0, NBO, KB); \
    ISSUE_B(0, NBO, KB); \
    ISSUE_B(1, NBO, KB); \
    VMCNT6(); \
    RAW_BARRIER(); \
    __builtin_amdgcn_s_setprio(1); \
    MM_F(0, 0, bfr0); \
    MM_F(0, 1, bfr1); \
    __builtin_amdgcn_s_setprio(0); \
    RAW_BARRIER(); \
    /* Phase B: ih = 1 */ \
    LDA_F(1, CB); \
    ISSUE_A(1, NBO, KB); \
    VMCNT2(); \
    RAW_BARRIER(); \
    __builtin_amdgcn_s_setprio(1); \
    MM_F(1, 0, bfr0); \
    MM_F(1, 1, bfr1); \
    __builtin_amdgcn_s_setprio(0); \
    RAW_BARRIER();

__global__ __launch_bounds__(512, 2) void gemm1_kernel(
    const bf16* __restrict__ xbf, const bf16* __restrict__ w1t,
    const float* __restrict__ b1, const int* __restrict__ counts,
    const int* __restrict__ offsets, const int* __restrict__ tokl,
    bf16* __restrict__ hbuf, int Hc, int cbase) {
  int bid = blockIdx.x;
  int q = gridDim.x >> 3;
  int L = (bid & 7) * q + (bid >> 3);
  int rt = L & 31;
  int g = L >> 5;
  int NT = Hc >> 8;
  int nt = g % NT, e = g / NT;
  int cnt = counts[e];
  if (rt * 256 >= cnt) return;
  __shared__ __align__(16) bf16 sA[2][256 * 64];
  __shared__ __align__(16) bf16 sB[2][256 * 64];
  int tid = threadIdx.x, lane = tid & 63, w = tid >> 6;
  int wm = w & 1, wn = w >> 1;
  int lf = lane & 15;
  int colx = ((lane >> 4) * 16) ^ ((lane & 7) << 4);
  int ra = tid >> 3;
  int ko = (tid & 7) * 16;
  int kox = ko ^ ((ra & 7) << 4);
  int dst = w * 1024;
  int hoff = offsets[e];
  const char* gA[4];
  const char* gB[4];
#pragma unroll
  for (int s = 0; s < 4; ++s) {
    int r = imin(rt * 256 + ra + s * 64, cnt - 1);
    int t = tokl[e * T_TOK + r];
    gA[s] = (const char*)(xbf + (size_t)t * DM) + kox;
    int col = cbase + nt * 256 + ra + s * 64;
    gB[s] = (const char*)(w1t + ((size_t)e * HD + col) * DM) + kox;
  }
  char* Al = (char*)sA;
  char* Bl = (char*)sB;
  const char* Ab = (const char*)sA;
  const char* Bb = (const char*)sB;
  f32x4 acc[2][2][4][2];
#pragma unroll
  for (int ih = 0; ih < 2; ++ih)
#pragma unroll
    for (int jh = 0; jh < 2; ++jh)
#pragma unroll
      for (int i = 0; i < 4; ++i)
#pragma unroll
        for (int j = 0; j < 2; ++j) acc[ih][jh][i][j] = {0.f, 0.f, 0.f, 0.f};
  bf16x8 af[8], bfr0[4], bfr1[4];
  const int K = DM / 64;  // 16
  // prologue: stage tile 0 in slot order Ah0, Bh0, Bh1, Ah1; drain all but Ah1
  ISSUE_A(0, 0, 0); ISSUE_B(0, 0, 0); ISSUE_B(1, 0, 0); ISSUE_A(1, 0, 0);
  VMCNT2();
  RAW_BARRIER();
  for (int k = 0; k < K; ++k) {
    int cb = (k & 1) * 32768;
    int nbo = ((k + 1) & 1) * 32768;
    int kb = (k + 1 < K) ? (k + 1) * 128 : 0;  // last iter: dummy refetch
    KTILE_BODY(cb, nbo, kb)
  }
  // epilogue
  int colq = lane & 15, rowq = (lane >> 4) * 4;
  size_t ebase = (size_t)e * HD + cbase + nt * 256;
  float b1v[2][2];
#pragma unroll
  for (int jh = 0; jh < 2; ++jh)
#pragma unroll
    for (int j = 0; j < 2; ++j)
      b1v[jh][j] = b1[ebase + 128 * jh + 32 * wn + 16 * j + colq];
#pragma unroll
  for (int ih = 0; ih < 2; ++ih) {
#pragma unroll
    for (int i = 0; i < 4; ++i) {
#pragma unroll
      for (int r = 0; r < 4; ++r) {
        int grow = rt * 256 + 128 * ih + 64 * wm + 16 * i + rowq + r;
        if (grow < cnt) {
          size_t hrow = (size_t)(hoff + grow) * Hc + nt * 256;
#pragma unroll
          for (int jh = 0; jh < 2; ++jh) {
#pragma unroll
            for (int j = 0; j < 2; ++j) {
              float v = acc[ih][jh][i][j][r] + b1v[jh][j];
              float gl = 0.5f * v * (1.f + erff(v * 0.70710678118654752f));
              hbuf[hrow + 128 * jh + 32 * wn + 16 * j + colq] = (bf16)gl;
            }
          }
        }
      }
    }
  }
}

__global__ __launch_bounds__(512, 2) void gemm2_kernel(
    const bf16* __restrict__ hbuf, const bf16* __restrict__ w2t,
    const float* __restrict__ b2, const int* __restrict__ counts,
    const int* __restrict__ offsets, const int* __restrict__ tokl,
    const float* __restrict__ wgt, float* __restrict__ out,
    int Hc, int cbase, float b2scale) {
  int bid = blockIdx.x;
  int q = gridDim.x >> 3;
  int L = (bid & 7) * q + (bid >> 3);
  int rt = L & 31;
  int g = L >> 5;
  const int NT = DM / 256;  // 4
  int nt = g % NT, e = g / NT;
  int cnt = counts[e];
  if (rt * 256 >= cnt) return;
  __shared__ __align__(16) bf16 sA[2][256 * 64];
  __shared__ __align__(16) bf16 sB[2][256 * 64];
  int tid = threadIdx.x, lane = tid & 63, w = tid >> 6;
  int wm = w & 1, wn = w >> 1;
  int lf = lane & 15;
  int colx = ((lane >> 4) * 16) ^ ((lane & 7) << 4);
  int ra = tid >> 3;
  int ko = (tid & 7) * 16;
  int kox = ko ^ ((ra & 7) << 4);
  int dst = w * 1024;
  int hoff = offsets[e];
  const char* gA[4];
  const char* gB[4];
#pragma unroll
  for (int s = 0; s < 4; ++s) {
    int r = imin(rt * 256 + ra + s * 64, cnt - 1);
    gA[s] = (const char*)(hbuf + (size_t)(hoff + r) * Hc) + kox;
    int col = nt * 256 + ra + s * 64;
    gB[s] = (const char*)(w2t + ((size_t)e * DM + col) * HD + cbase) + kox;
  }
  char* Al = (char*)sA;
  char* Bl = (char*)sB;
  const char* Ab = (const char*)sA;
  const char* Bb = (const char*)sB;
  f32x4 acc[2][2][4][2];
#pragma unroll
  for (int ih = 0; ih < 2; ++ih)
#pragma unroll
    for (int jh = 0; jh < 2; ++jh)
#pragma unroll
      for (int i = 0; i < 4; ++i)
#pragma unroll
        for (int j = 0; j < 2; ++j) acc[ih][jh][i][j] = {0.f, 0.f, 0.f, 0.f};
  bf16x8 af[8], bfr0[4], bfr1[4];
  const int K = Hc / 64;
  ISSUE_A(0, 0, 0); ISSUE_B(0, 0, 0); ISSUE_B(1, 0, 0); ISSUE_A(1, 0, 0);
  VMCNT2();
  RAW_BARRIER();
  for (int k = 0; k < K; ++k) {
    int cb = (k & 1) * 32768;
    int nbo = ((k + 1) & 1) * 32768;
    int kb = (k + 1 < K) ? (k + 1) * 128 : 0;
    KTILE_BODY(cb, nbo, kb)
  }
  int colq = lane & 15, rowq = (lane >> 4) * 4;
  float b2v[2][2];
#pragma unroll
  for (int jh = 0; jh < 2; ++jh)
#pragma unroll
    for (int j = 0; j < 2; ++j)
      b2v[jh][j] = b2[(size_t)e * DM + nt * 256 + 128 * jh + 32 * wn + 16 * j + colq] * b2scale;
#pragma unroll
  for (int ih = 0; ih < 2; ++ih) {
#pragma unroll
    for (int i = 0; i < 4; ++i) {
#pragma unroll
      for (int r = 0; r < 4; ++r) {
        int grow = rt * 256 + 128 * ih + 64 * wm + 16 * i + rowq + r;
        if (grow < cnt) {
          float wv = wgt[e * T_TOK + grow];
          int tk = tokl[e * T_TOK + grow];
          float* orow = out + (size_t)tk * DM + nt * 256;
#pragma unroll
          for (int jh = 0; jh < 2; ++jh) {
#pragma unroll
            for (int j = 0; j < 2; ++j)
              atomicAdd(orow + 128 * jh + 32 * wn + 16 * j + colq,
                        wv * (acc[ih][jh][i][j][r] + b2v[jh][j]));
          }
        }
      }
    }
  }
}

extern "C" void kernel_launch(void* const* d_in, const int* in_sizes, int n_in,
                              void* d_out, int out_size, void* d_ws, size_t ws_size,
                              hipStream_t stream) {
  const float* x  = (const float*)d_in[0];
  const float* Wg = (const float*)d_in[1];
  const float* bg = (const float*)d_in[2];
  const float* W1 = (const float*)d_in[3];
  const float* b1 = (const float*)d_in[4];
  const float* W2 = (const float*)d_in[5];
  const float* b2 = (const float*)d_in[6];
  float* out = (float*)d_out;

  char* ws = (char*)d_ws;
  size_t off = 0;
  auto alloc = [&](size_t bytes) -> void* {
    void* p = ws + off;
    off = (off + bytes + 255) & ~(size_t)255;
    return p;
  };
  int*   counts  = (int*)alloc(NE * 4);
  int*   offsets = (int*)alloc((NE + 1) * 4);
  int*   tokl    = (int*)alloc((size_t)NE * T_TOK * 4);
  float* wgt     = (float*)alloc((size_t)NE * T_TOK * 4);
  bf16*  xbf     = (bf16*)alloc((size_t)T_TOK * DM * 2);
  bf16*  w1t     = (bf16*)alloc((size_t)NE * HD * DM * 2);
  bf16*  w2t     = (bf16*)alloc((size_t)NE * DM * HD * 2);
  size_t remain = ws_size > off ? ws_size - off : 0;
  int Hc = HD;
  while (Hc > 256 && (size_t)2 * T_TOK * Hc * 2 > remain) Hc >>= 1;  // h rows total = 2*T
  bf16* hbuf = (bf16*)alloc((size_t)2 * T_TOK * Hc * 2);

  zero_kernel<<<4096, 256, 0, stream>>>(out, counts);
  transpose_cvt_kernel<<<dim3(HD / 64, DM / 64, NE), 256, 0, stream>>>(W1, w1t, DM, HD);
  transpose_cvt_kernel<<<dim3(DM / 64, HD / 64, NE), 256, 0, stream>>>(W2, w2t, HD, DM);
  gating_kernel<<<T_TOK / 4, 256, 0, stream>>>(x, Wg, bg, counts, tokl, wgt, xbf);
  scan_kernel<<<1, 64, 0, stream>>>(counts, offsets);

  int nchunk = HD / Hc;
  for (int c = 0; c < nchunk; ++c) {
    gemm1_kernel<<<NE * (Hc / 256) * (T_TOK / 256), 512, 0, stream>>>(
        xbf, w1t, b1, counts, offsets, tokl, hbuf, Hc, c * Hc);
    gemm2_kernel<<<NE * (DM / 256) * (T_TOK / 256), 512, 0, stream>>>(
        hbuf, w2t, b2, counts, offsets, tokl, wgt, out, Hc, c * Hc, c == 0 ? 1.f : 0.f);
  }
}